// Round 11
// baseline (175.757 us; speedup 1.0000x reference)
//
#include <hip/hip_runtime.h>
#include <cstddef>
#include <cstdint>

#define B_ 4
#define C_ 256
#define N_ 4096
/* frag-layout operand planes:
   qf [b][256 ntile][64 lane][8]  bf16  (q channels 0..31, log2e folded via BN)
   kf [b][256 ntile][64 lane][8]  bf16  (k channels 32..63)
   df [b][16 ctile][128 nchunk][64 lane][8] bf16                              */
#define KF_OFF_B  ((size_t)1024 * 1024)
#define DF_OFF_B  ((size_t)2 * 1024 * 1024)
#define SUM_OFF_B ((size_t)10 * 1024 * 1024)       /* sum[320],sumsq[320] */
#define ML_OFF_B  (SUM_OFF_B + 1280 * 4)           /* (unused now) */
#define XH_OFF_B  (ML_OFF_B + 524288)              /* xt hi [b][n][256] bf16: 8 MB */
#define XL_OFF_B  (XH_OFF_B + (size_t)8 * 1024 * 1024)
#define WH_OFF_B  (XL_OFF_B + (size_t)8 * 1024 * 1024)
#define WL_OFF_B  (WH_OFF_B + 163840)
#define LOG2E 1.4426950408889634f

typedef unsigned short bfraw;
typedef __attribute__((ext_vector_type(8))) short short8;
typedef __attribute__((ext_vector_type(4))) float float4v;
typedef __attribute__((ext_vector_type(4))) bfraw bfraw4;

__device__ inline bfraw f2bf(float f) {
    union { float f; uint32_t u; } c; c.f = f;
    uint32_t u = c.u;
    u += 0x7fffu + ((u >> 16) & 1u);     // RNE
    return (bfraw)(u >> 16);
}
__device__ inline float bf2f(bfraw h) {
    union { uint32_t u; float f; } c; c.u = ((uint32_t)h) << 16;
    return c.f;
}
#if __has_builtin(__builtin_amdgcn_exp2f)
__device__ inline float EXP2(float x) { return __builtin_amdgcn_exp2f(x); }
#else
__device__ inline float EXP2(float x) { return exp2f(x); }
#endif
__device__ inline uint32_t pack2(float a, float b) {
    union { float f; uint32_t u; } ca, cb; ca.f = a; cb.f = b;
#if __has_builtin(__builtin_amdgcn_perm)
    return __builtin_amdgcn_perm(cb.u + 0x8000u, ca.u + 0x8000u, 0x07060302u);
#else
    return ((ca.u + 0x8000u) >> 16) | ((cb.u + 0x8000u) & 0xffff0000u);
#endif
}

// ---------------------------------------------------------------------------
// prep: blocks 0..1023 = transpose+split x -> xt hi/lo [b][n][256] bf16;
//       blocks 1024..1103 = split w into bf16 hi/lo planes [320][256];
//       block 1024 also zeroes BN sums.
// ---------------------------------------------------------------------------
__global__ __launch_bounds__(256) void prep_kernel(
    const float* __restrict__ x,
    const float* __restrict__ w1, const float* __restrict__ w2,
    const float* __restrict__ w3, uint8_t* __restrict__ wsb)
{
    __shared__ float Ls[64][65];
    if (blockIdx.x >= 1024) {                    // ---- wsplit path ----
        int bid = blockIdx.x - 1024;
        if (bid == 0) {
            float* sums = (float*)(wsb + SUM_OFF_B);
            for (int i = threadIdx.x; i < 640; i += 256) sums[i] = 0.f;
        }
        bfraw* wh = (bfraw*)(wsb + WH_OFF_B);
        bfraw* wl = (bfraw*)(wsb + WL_OFF_B);
        int idx4 = (bid * 256 + threadIdx.x) * 4;
        int ch = idx4 >> 8, k = idx4 & 255;
        const float* wr = (ch < 32) ? (w1 + ch * C_)
                          : (ch < 64) ? (w2 + (ch - 32) * C_)
                                      : (w3 + (ch - 64) * C_);
        float4 v = *(const float4*)&wr[k];
        float va[4] = {v.x, v.y, v.z, v.w};
        bfraw4 h, l;
#pragma unroll
        for (int j = 0; j < 4; ++j) {
            h[j] = f2bf(va[j]);
            l[j] = f2bf(va[j] - bf2f(h[j]));
        }
        *(bfraw4*)&wh[idx4] = h;
        *(bfraw4*)&wl[idx4] = l;
        return;
    }
    // ---- xtsplit path ----
    bfraw* xh = (bfraw*)(wsb + XH_OFF_B);
    bfraw* xl = (bfraw*)(wsb + XL_OFF_B);
    const int id = blockIdx.x;
    const int b  = id >> 8;
    const int c0 = ((id >> 6) & 3) << 6;
    const int n0 = (id & 63) << 6;
    const int t  = threadIdx.x;
    {
        int cl = t >> 4, nc = (t & 15) << 2;
#pragma unroll
        for (int i = 0; i < 4; ++i) {
            float4 v = *(const float4*)&x[((size_t)b * C_ + c0 + cl + i * 16) * N_ + n0 + nc];
            Ls[cl + i * 16][nc + 0] = v.x;
            Ls[cl + i * 16][nc + 1] = v.y;
            Ls[cl + i * 16][nc + 2] = v.z;
            Ls[cl + i * 16][nc + 3] = v.w;
        }
    }
    __syncthreads();
    int nl = t >> 2, seg = t & 3;
    bfraw hb[16], lb[16];
#pragma unroll
    for (int j = 0; j < 16; ++j) {
        float v = Ls[seg * 16 + j][nl];
        bfraw h = f2bf(v);
        hb[j] = h;
        lb[j] = f2bf(v - bf2f(h));
    }
    size_t base = ((size_t)b * N_ + n0 + nl) * 256 + c0 + seg * 16;
    *(short8*)&xh[base]     = *(short8*)&hb[0];
    *(short8*)&xh[base + 8] = *(short8*)&hb[8];
    *(short8*)&xl[base]     = *(short8*)&lb[0];
    *(short8*)&xl[base + 8] = *(short8*)&lb[8];
}

// ---------------------------------------------------------------------------
// MFMA ygemm (3-term bf16 split); epilogue stores q/k/d in FRAG LAYOUT.
// R9 epilogue: q/k b64 stores; d LDS-transpose + 1KB coalesced stores.
// ---------------------------------------------------------------------------
__global__ __launch_bounds__(256, 2) void ygemm_kernel(uint8_t* __restrict__ wsb)
{
    const bfraw* xh = (const bfraw*)(wsb + XH_OFF_B);
    const bfraw* xl = (const bfraw*)(wsb + XL_OFF_B);
    const bfraw* wh = (const bfraw*)(wsb + WH_OFF_B);
    const bfraw* wl = (const bfraw*)(wsb + WL_OFF_B);
    bfraw* qf  = (bfraw*)wsb;
    bfraw* kfp = (bfraw*)(wsb + KF_OFF_B);
    bfraw* dfp = (bfraw*)(wsb + DF_OFF_B);
    float* sums  = (float*)(wsb + SUM_OFF_B);
    float* sumsq = sums + 320;
    __shared__ float redS[4][64], redQ[4][64];
    __shared__ bfraw Td[4][64 * 40];             // per-wave d-transpose staging

    const int bx = blockIdx.x;
    const int by = blockIdx.y;
    const int b  = bx >> 5;
    const int n0 = (bx << 7) & (N_ - 1);
    const int t = threadIdx.x, w = t >> 6, l = t & 63, lq = l & 15, lg = l >> 4;
    const int nw = n0 + w * 32;

    float4v acc[4][2];
#pragma unroll
    for (int i = 0; i < 4; ++i)
#pragma unroll
        for (int j = 0; j < 2; ++j) acc[i][j] = (float4v){0.f, 0.f, 0.f, 0.f};

    for (int s = 0; s < 8; ++s) {
        const int k0 = s * 32;
        short8 ah[4], al[4], bh[2], bl[2];
#pragma unroll
        for (int ct = 0; ct < 4; ++ct) {
            size_t off = (size_t)(by * 64 + ct * 16 + lq) * 256 + k0 + lg * 8;
            ah[ct] = *(const short8*)&wh[off];
            al[ct] = *(const short8*)&wl[off];
        }
#pragma unroll
        for (int nt = 0; nt < 2; ++nt) {
            size_t off = ((size_t)b * N_ + nw + nt * 16 + lq) * 256 + k0 + lg * 8;
            bh[nt] = *(const short8*)&xh[off];
            bl[nt] = *(const short8*)&xl[off];
        }
#pragma unroll
        for (int ct = 0; ct < 4; ++ct)
#pragma unroll
            for (int nt = 0; nt < 2; ++nt) {
                acc[ct][nt] = __builtin_amdgcn_mfma_f32_16x16x32_bf16(ah[ct], bh[nt], acc[ct][nt], 0, 0, 0);
                acc[ct][nt] = __builtin_amdgcn_mfma_f32_16x16x32_bf16(al[ct], bh[nt], acc[ct][nt], 0, 0, 0);
                acc[ct][nt] = __builtin_amdgcn_mfma_f32_16x16x32_bf16(ah[ct], bl[nt], acc[ct][nt], 0, 0, 0);
            }
    }
#pragma unroll
    for (int ct = 0; ct < 4; ++ct) {
        float sv[4], qv[4];
#pragma unroll
        for (int r = 0; r < 4; ++r) {
            float a0 = acc[ct][0][r], a1 = acc[ct][1][r];
            sv[r] = a0 + a1;
            qv[r] = a0 * a0 + a1 * a1;
#pragma unroll
            for (int m = 1; m < 16; m <<= 1) {
                sv[r] += __shfl_xor(sv[r], m);
                qv[r] += __shfl_xor(qv[r], m);
            }
        }
        if (lq == 0) {
#pragma unroll
            for (int r = 0; r < 4; ++r) {
                redS[w][ct * 16 + lg * 4 + r] = sv[r];
                redQ[w][ct * 16 + lg * 4 + r] = qv[r];
            }
        }
    }
    __syncthreads();
    if (t < 64) {
        float s = redS[0][t] + redS[1][t] + redS[2][t] + redS[3][t];
        float q = redQ[0][t] + redQ[1][t] + redQ[2][t] + redQ[3][t];
        atomicAdd(&sums[by * 64 + t], s);
        atomicAdd(&sumsq[by * 64 + t], q);
    }
    if (by == 0) {
        // q/k frag layout: tile = b*256 + n>>4; lane = (n&15)|(((c>>3)&3)<<4); j = c&7
        // c0 = ct*16+lg*4: (c>>3)&3 constant over r=0..3; c&7 = (lg&1)*4 + r  -> b64 store
#pragma unroll
        for (int ct = 0; ct < 4; ++ct)
#pragma unroll
            for (int nt = 0; nt < 2; ++nt) {
                int n = nw + nt * 16 + lq;
                int c0 = ct * 16 + lg * 4;
                bfraw4 v;
#pragma unroll
                for (int r = 0; r < 4; ++r) v[r] = f2bf(acc[ct][nt][r]);
                size_t addr = ((size_t)(b << 8) + (n >> 4)) * 512
                            + (size_t)(((n & 15) | (((c0 >> 3) & 3) << 4)) << 3) + (c0 & 7);
                if (c0 < 32) *(bfraw4*)&qf[addr] = v;
                else         *(bfraw4*)&kfp[addr] = v;
            }
    } else {
        // d path: stage [cl][nl] in LDS (cl = local cg 0..63, nl = local n 0..31),
        // then read in A-frag order and store 1KB coalesced per tile.
#pragma unroll
        for (int ct = 0; ct < 4; ++ct)
#pragma unroll
            for (int nt = 0; nt < 2; ++nt)
#pragma unroll
                for (int r = 0; r < 4; ++r) {
                    int cl = ct * 16 + lg * 4 + r;
                    int nl = nt * 16 + lq;
                    Td[w][cl * 40 + nl] = f2bf(acc[ct][nt][r]);
                }
        __syncthreads();
#pragma unroll
        for (int ctl = 0; ctl < 4; ++ctl) {
            short8 vv = *(const short8*)&Td[w][(ctl * 16 + (l & 15)) * 40 + (l >> 4) * 8];
            size_t addr = (((size_t)(b << 4) + (by - 1) * 4 + ctl) * 128 + (nw >> 5)) * 512
                        + (size_t)l * 8;
            *(short8*)&dfp[addr] = vv;
        }
    }
}

// ---------------------------------------------------------------------------
// in-place bf16 relu(sc*y + bi) over frag-layout planes; BN finalize inline.
// ---------------------------------------------------------------------------
__device__ inline void bn_coef(const float* __restrict__ sums,
                               const float* __restrict__ g1, const float* __restrict__ b1,
                               const float* __restrict__ g2, const float* __restrict__ b2,
                               const float* __restrict__ g3, const float* __restrict__ b3,
                               int ch, float& sc, float& bi)
{
    const float inv = 1.0f / (float)(B_ * N_);
    float mean = sums[ch] * inv;
    float var  = sums[320 + ch] * inv - mean * mean;
    float g, bb;
    if (ch < 32)      { g = g1[ch];      bb = b1[ch]; }
    else if (ch < 64) { g = g2[ch - 32]; bb = b2[ch - 32]; }
    else              { g = g3[ch - 64]; bb = b3[ch - 64]; }
    sc = g * rsqrtf(var + 1e-5f);
    bi = bb - sc * mean;
    if (ch < 32) { sc *= LOG2E; bi *= LOG2E; }
}

__global__ __launch_bounds__(256) void affine_kernel(
    uint8_t* __restrict__ wsb,
    const float* __restrict__ g1, const float* __restrict__ b1,
    const float* __restrict__ g2, const float* __restrict__ b2,
    const float* __restrict__ g3, const float* __restrict__ b3)
{
    bfraw* base = (bfraw*)wsb;
    const float* sums = (const float*)(wsb + SUM_OFF_B);
    size_t i8 = ((size_t)blockIdx.x * 256 + threadIdx.x) * 8;
    bfraw4 v0 = *(bfraw4*)&base[i8];
    bfraw4 v1 = *(bfraw4*)&base[i8 + 4];
    if (i8 < 1048576) {                          // qf or kf
        int ch0 = (((int)(i8 >> 7)) & 3) * 8 + ((i8 < 524288) ? 0 : 32);
        float sa[8], ca[8];
#pragma unroll
        for (int j = 0; j < 8; ++j)
            bn_coef(sums, g1, b1, g2, b2, g3, b3, ch0 + j, sa[j], ca[j]);
#pragma unroll
        for (int j = 0; j < 4; ++j) {
            v0[j] = f2bf(fmaxf(0.f, fmaf(sa[j],     bf2f(v0[j]), ca[j])));
            v1[j] = f2bf(fmaxf(0.f, fmaf(sa[j + 4], bf2f(v1[j]), ca[j + 4])));
        }
    } else {                                     // df
        size_t rel = i8 - 1048576;
        int ch = 64 + (((int)(rel >> 16)) & 15) * 16 + (((int)(rel >> 3)) & 15);
        float s, b;
        bn_coef(sums, g1, b1, g2, b2, g3, b3, ch, s, b);
#pragma unroll
        for (int j = 0; j < 4; ++j) {
            v0[j] = f2bf(fmaxf(0.f, fmaf(s, bf2f(v0[j]), b)));
            v1[j] = f2bf(fmaxf(0.f, fmaf(s, bf2f(v1[j]), b)));
        }
    }
    *(bfraw4*)&base[i8] = v0;
    *(bfraw4*)&base[i8 + 4] = v1;
}

// ---------------------------------------------------------------------------
// flash v11: PRODUCER/CONSUMER wave split.
// R10 accounting: phase floor = per-CU LDS bfr (8 waves x full-P re-read =
// 3100cyc) + d L2 (2340cyc) executed SEQUENTIALLY by every wave.  Split:
// 4 score waves (w<4: q-tile w, all 16 k-tiles/window) produce Pl[t&1];
// 4 PV waves (w>=4: ctiles {w-4,+4,+8,+12} x 4 q-tiles) consume Pl[(t-1)&1].
// Producer interval t runs CONCURRENTLY with consumer interval t-1 on
// different pipes (VALU+L2k vs LDS+MFMA+L2d).  bfr LDS traffic halves
// (4 waves x full P; each bfr read feeds 4 MFMA); d-dup stays 1 (each ctile
// owned by one wave).  17 uniform barriers + 1 for lsh publish.
// Fixed-shift softmax P = exp2(s-16) (validated R7-R10).
// LDS: Pl 2x32KB + lsh = 64.5KB, grid 256 = 1 block/CU.
// ---------------------------------------------------------------------------
__global__ __launch_bounds__(512, 2) void flash_kernel(
    const float* __restrict__ x, const uint8_t* __restrict__ wsb,
    float* __restrict__ out)
{
    const bfraw* qf  = (const bfraw*)wsb;
    const bfraw* kfp = (const bfraw*)(wsb + KF_OFF_B);
    const bfraw* dfp = (const bfraw*)(wsb + DF_OFF_B);
    __shared__ bfraw Pl[2][64 * 256];            // 64 KB
    __shared__ float lsh[64];                    // sum per q

    const int id  = blockIdx.x;
    const int b   = id & 3;
    const int n0q = (id >> 2) << 6;
    const int tid = threadIdx.x;
    const int w   = tid >> 6;                    // 0..7
    const int l   = tid & 63;
    const int lq  = l & 15;
    const int lg  = l >> 4;
    const int sw  = lq & 7;
    const float4v zv = {-16.f, -16.f, -16.f, -16.f};   // fixed log2 shift

    // ---- producer state (w < 4) ----
    short8 qfrag;
    short8 kfr[8];
    float ps = 0.f;
    int qrow = 0;
    // ---- consumer state (w >= 4) ----
    const int wp = w & 3;                        // ctiles wp, wp+4, wp+8, wp+12
    float4v acc[4][4];                           // [i][qt]
    short8 dfr[4][4];                            // rolling 4-chunk window

    if (w < 4) {
        qrow = w * 16 + lq;
        qfrag = *(const short8*)&qf[((size_t)(b * 256 + (n0q >> 4) + w)) * 512 + l * 8];
#pragma unroll
        for (int kt = 0; kt < 8; ++kt)           // window 0, half 0
            kfr[kt] = *(const short8*)&kfp[((size_t)(b * 256 + kt)) * 512 + l * 8];
    } else {
#pragma unroll
        for (int i = 0; i < 4; ++i)
#pragma unroll
            for (int j = 0; j < 4; ++j) acc[i][j] = (float4v){0.f, 0.f, 0.f, 0.f};
#pragma unroll
        for (int i = 0; i < 4; ++i)
#pragma unroll
            for (int c = 0; c < 4; ++c)          // window 0, chunks 0..3
                dfr[i][c] = *(const short8*)&dfp[(((size_t)(b * 16 + wp + 4 * i)) * 128 + c) * 512 + l * 8];
    }

    for (int t = 0; t <= 16; ++t) {
        if (w < 4) {
            if (t < 16) {                        // ---- produce window t ----
                const int ib = t & 1;
                // half 0 (kt 0..7): kfr already loaded
                float4v st[8];
#pragma unroll
                for (int kt = 0; kt < 8; ++kt)
                    st[kt] = __builtin_amdgcn_mfma_f32_16x16x32_bf16(kfr[kt], qfrag, zv, 0, 0, 0);
#pragma unroll
                for (int kt = 0; kt < 8; ++kt)   // prefetch half 1
                    kfr[kt] = *(const short8*)&kfp[((size_t)(b * 256 + t * 16 + 8 + kt)) * 512 + l * 8];
#pragma unroll
                for (int kt = 0; kt < 8; ++kt) {
                    float e0 = EXP2(st[kt][0]);
                    float e1 = EXP2(st[kt][1]);
                    float e2 = EXP2(st[kt][2]);
                    float e3 = EXP2(st[kt][3]);
                    ps += (e0 + e1) + (e2 + e3);
                    uint2 pd = {pack2(e0, e1), pack2(e2, e3)};
                    int g = (2 * kt + (lg >> 1)) ^ sw;
                    *(uint2*)&Pl[ib][qrow * 256 + g * 8 + (lg & 1) * 4] = pd;
                }
                // half 1 (kt 8..15)
#pragma unroll
                for (int kt = 0; kt < 8; ++kt)
                    st[kt] = __builtin_amdgcn_mfma_f32_16x16x32_bf16(kfr[kt], qfrag, zv, 0, 0, 0);
#pragma unroll
                for (int kt = 0; kt < 8; ++kt)   // prefetch next window half 0
                    kfr[kt] = *(const short8*)&kfp[((size_t)(b * 256 + (((t + 1) & 15) * 16) + kt)) * 512 + l * 8];
#pragma unroll
                for (int kt = 0; kt < 8; ++kt) {
                    float e0 = EXP2(st[kt][0]);
                    float e1 = EXP2(st[kt][1]);
                    float e2 = EXP2(st[kt][2]);
                    float e3 = EXP2(st[kt][3]);
                    ps += (e0 + e1) + (e2 + e3);
                    uint2 pd = {pack2(e0, e1), pack2(e2, e3)};
                    int g = (2 * (kt + 8) + (lg >> 1)) ^ sw;
                    *(uint2*)&Pl[ib][qrow * 256 + g * 8 + (lg & 1) * 4] = pd;
                }
            }
        } else {
            if (t >= 1) {                        // ---- consume window t-1 ----
                const int wd = t - 1;
                const int ib = wd & 1;
#pragma unroll
                for (int ch = 0; ch < 8; ++ch) {
                    short8 bfr[4];
                    int g = (ch * 4 + lg) ^ sw;
#pragma unroll
                    for (int qt = 0; qt < 4; ++qt)
                        bfr[qt] = *(const short8*)&Pl[ib][(qt * 16 + lq) * 256 + g * 8];
                    __builtin_amdgcn_s_setprio(1);
#pragma unroll
                    for (int i = 0; i < 4; ++i)
#pragma unroll
                        for (int qt = 0; qt < 4; ++qt)
                            acc[i][qt] = __builtin_amdgcn_mfma_f32_16x16x32_bf16(dfr[i][ch & 3], bfr[qt], acc[i][qt], 0, 0, 0);
                    __builtin_amdgcn_s_setprio(0);
                    // rolling d reload: ch<4 -> this window's chunks ch+4; else next window's
                    int rwd = (ch < 4) ? wd : ((wd + 1) & 15);
                    int rch = (ch < 4) ? (ch + 4) : (ch - 4);
#pragma unroll
                    for (int i = 0; i < 4; ++i)
                        dfr[i][ch & 3] = *(const short8*)&dfp[(((size_t)(b * 16 + wp + 4 * i)) * 128 + rwd * 8 + rch) * 512 + l * 8];
                }
            }
        }
        __syncthreads();
    }
    // ---- publish per-q sums (producers), then consumers write out ----
    if (w < 4) {
        ps += __shfl_xor(ps, 16);
        ps += __shfl_xor(ps, 32);
        if (lg == 0) lsh[qrow] = ps;
    }
    __syncthreads();
    if (w >= 4) {
        float inv[4];
#pragma unroll
        for (int qt = 0; qt < 4; ++qt)
            inv[qt] = 1.0f / lsh[qt * 16 + lq];
#pragma unroll
        for (int i = 0; i < 4; ++i) {
            int ctg = wp + 4 * i;
#pragma unroll
            for (int r = 0; r < 4; ++r) {
                int c = ctg * 16 + lg * 4 + r;
                size_t base = ((size_t)b * C_ + c) * N_ + n0q;
#pragma unroll
                for (int qt = 0; qt < 4; ++qt) {
                    size_t idx = base + qt * 16 + lq;
                    out[idx] = x[idx] + acc[i][qt][r] * inv[qt];
                }
            }
        }
    }
}

extern "C" void kernel_launch(void* const* d_in, const int* in_sizes, int n_in,
                              void* d_out, int out_size, void* d_ws, size_t ws_size,
                              hipStream_t stream) {
    (void)in_sizes; (void)n_in; (void)out_size; (void)ws_size;
    const float* x  = (const float*)d_in[0];
    const float* w1 = (const float*)d_in[1];
    const float* w2 = (const float*)d_in[2];
    const float* w3 = (const float*)d_in[3];
    const float* g1 = (const float*)d_in[4];
    const float* b1 = (const float*)d_in[5];
    const float* g2 = (const float*)d_in[6];
    const float* b2 = (const float*)d_in[7];
    const float* g3 = (const float*)d_in[8];
    const float* b3 = (const float*)d_in[9];
    uint8_t* wsb = (uint8_t*)d_ws;
    float* outp = (float*)d_out;

    prep_kernel<<<1104, 256, 0, stream>>>(x, w1, w2, w3, wsb);
    ygemm_kernel<<<dim3(128, 5), 256, 0, stream>>>(wsb);
    affine_kernel<<<2560, 256, 0, stream>>>(wsb, g1, b1, g2, b2, g3, b3);
    flash_kernel<<<256, 512, 0, stream>>>(x, wsb, outp);
}

// Round 12
// 172.466 us; speedup vs baseline: 1.0191x; 1.0191x over previous
//
#include <hip/hip_runtime.h>
#include <cstddef>
#include <cstdint>

#define B_ 4
#define C_ 256
#define N_ 4096
/* frag-layout operand planes:
   qf [b][256 ntile][64 lane][8]  bf16  (q channels 0..31, log2e folded via BN)
   kf [b][256 ntile][64 lane][8]  bf16  (k channels 32..63)
   df [b][16 ctile][128 nchunk][64 lane][8] bf16                              */
#define KF_OFF_B  ((size_t)1024 * 1024)
#define DF_OFF_B  ((size_t)2 * 1024 * 1024)
#define SUM_OFF_B ((size_t)10 * 1024 * 1024)       /* sum[320],sumsq[320] */
#define ML_OFF_B  (SUM_OFF_B + 1280 * 4)           /* (unused now) */
#define XH_OFF_B  (ML_OFF_B + 524288)              /* xt hi [b][n][256] bf16: 8 MB */
#define XL_OFF_B  (XH_OFF_B + (size_t)8 * 1024 * 1024)
#define WH_OFF_B  (XL_OFF_B + (size_t)8 * 1024 * 1024)
#define WL_OFF_B  (WH_OFF_B + 163840)
#define LOG2E 1.4426950408889634f

typedef unsigned short bfraw;
typedef __attribute__((ext_vector_type(8))) short short8;
typedef __attribute__((ext_vector_type(4))) float float4v;
typedef __attribute__((ext_vector_type(4))) bfraw bfraw4;

__device__ inline bfraw f2bf(float f) {
    union { float f; uint32_t u; } c; c.f = f;
    uint32_t u = c.u;
    u += 0x7fffu + ((u >> 16) & 1u);     // RNE
    return (bfraw)(u >> 16);
}
__device__ inline float bf2f(bfraw h) {
    union { uint32_t u; float f; } c; c.u = ((uint32_t)h) << 16;
    return c.f;
}
#if __has_builtin(__builtin_amdgcn_exp2f)
__device__ inline float EXP2(float x) { return __builtin_amdgcn_exp2f(x); }
#else
__device__ inline float EXP2(float x) { return exp2f(x); }
#endif
__device__ inline uint32_t pack2(float a, float b) {
    union { float f; uint32_t u; } ca, cb; ca.f = a; cb.f = b;
#if __has_builtin(__builtin_amdgcn_perm)
    return __builtin_amdgcn_perm(cb.u + 0x8000u, ca.u + 0x8000u, 0x07060302u);
#else
    return ((ca.u + 0x8000u) >> 16) | ((cb.u + 0x8000u) & 0xffff0000u);
#endif
}

// ---------------------------------------------------------------------------
// prep: blocks 0..1023 = transpose+split x -> xt hi/lo [b][n][256] bf16;
//       blocks 1024..1103 = split w into bf16 hi/lo planes [320][256];
//       block 1024 also zeroes BN sums.
// ---------------------------------------------------------------------------
__global__ __launch_bounds__(256) void prep_kernel(
    const float* __restrict__ x,
    const float* __restrict__ w1, const float* __restrict__ w2,
    const float* __restrict__ w3, uint8_t* __restrict__ wsb)
{
    __shared__ float Ls[64][65];
    if (blockIdx.x >= 1024) {                    // ---- wsplit path ----
        int bid = blockIdx.x - 1024;
        if (bid == 0) {
            float* sums = (float*)(wsb + SUM_OFF_B);
            for (int i = threadIdx.x; i < 640; i += 256) sums[i] = 0.f;
        }
        bfraw* wh = (bfraw*)(wsb + WH_OFF_B);
        bfraw* wl = (bfraw*)(wsb + WL_OFF_B);
        int idx4 = (bid * 256 + threadIdx.x) * 4;
        int ch = idx4 >> 8, k = idx4 & 255;
        const float* wr = (ch < 32) ? (w1 + ch * C_)
                          : (ch < 64) ? (w2 + (ch - 32) * C_)
                                      : (w3 + (ch - 64) * C_);
        float4 v = *(const float4*)&wr[k];
        float va[4] = {v.x, v.y, v.z, v.w};
        bfraw4 h, l;
#pragma unroll
        for (int j = 0; j < 4; ++j) {
            h[j] = f2bf(va[j]);
            l[j] = f2bf(va[j] - bf2f(h[j]));
        }
        *(bfraw4*)&wh[idx4] = h;
        *(bfraw4*)&wl[idx4] = l;
        return;
    }
    // ---- xtsplit path ----
    bfraw* xh = (bfraw*)(wsb + XH_OFF_B);
    bfraw* xl = (bfraw*)(wsb + XL_OFF_B);
    const int id = blockIdx.x;
    const int b  = id >> 8;
    const int c0 = ((id >> 6) & 3) << 6;
    const int n0 = (id & 63) << 6;
    const int t  = threadIdx.x;
    {
        int cl = t >> 4, nc = (t & 15) << 2;
#pragma unroll
        for (int i = 0; i < 4; ++i) {
            float4 v = *(const float4*)&x[((size_t)b * C_ + c0 + cl + i * 16) * N_ + n0 + nc];
            Ls[cl + i * 16][nc + 0] = v.x;
            Ls[cl + i * 16][nc + 1] = v.y;
            Ls[cl + i * 16][nc + 2] = v.z;
            Ls[cl + i * 16][nc + 3] = v.w;
        }
    }
    __syncthreads();
    int nl = t >> 2, seg = t & 3;
    bfraw hb[16], lb[16];
#pragma unroll
    for (int j = 0; j < 16; ++j) {
        float v = Ls[seg * 16 + j][nl];
        bfraw h = f2bf(v);
        hb[j] = h;
        lb[j] = f2bf(v - bf2f(h));
    }
    size_t base = ((size_t)b * N_ + n0 + nl) * 256 + c0 + seg * 16;
    *(short8*)&xh[base]     = *(short8*)&hb[0];
    *(short8*)&xh[base + 8] = *(short8*)&hb[8];
    *(short8*)&xl[base]     = *(short8*)&lb[0];
    *(short8*)&xl[base + 8] = *(short8*)&lb[8];
}

// ---------------------------------------------------------------------------
// MFMA ygemm (3-term bf16 split); epilogue stores q/k/d in FRAG LAYOUT.
// R9 epilogue: q/k b64 stores; d LDS-transpose + 1KB coalesced stores.
// (R10's unroll-2 reverted: neutral-to-negative.)
// ---------------------------------------------------------------------------
__global__ __launch_bounds__(256, 2) void ygemm_kernel(uint8_t* __restrict__ wsb)
{
    const bfraw* xh = (const bfraw*)(wsb + XH_OFF_B);
    const bfraw* xl = (const bfraw*)(wsb + XL_OFF_B);
    const bfraw* wh = (const bfraw*)(wsb + WH_OFF_B);
    const bfraw* wl = (const bfraw*)(wsb + WL_OFF_B);
    bfraw* qf  = (bfraw*)wsb;
    bfraw* kfp = (bfraw*)(wsb + KF_OFF_B);
    bfraw* dfp = (bfraw*)(wsb + DF_OFF_B);
    float* sums  = (float*)(wsb + SUM_OFF_B);
    float* sumsq = sums + 320;
    __shared__ float redS[4][64], redQ[4][64];
    __shared__ bfraw Td[4][64 * 40];             // per-wave d-transpose staging

    const int bx = blockIdx.x;
    const int by = blockIdx.y;
    const int b  = bx >> 5;
    const int n0 = (bx << 7) & (N_ - 1);
    const int t = threadIdx.x, w = t >> 6, l = t & 63, lq = l & 15, lg = l >> 4;
    const int nw = n0 + w * 32;

    float4v acc[4][2];
#pragma unroll
    for (int i = 0; i < 4; ++i)
#pragma unroll
        for (int j = 0; j < 2; ++j) acc[i][j] = (float4v){0.f, 0.f, 0.f, 0.f};

    for (int s = 0; s < 8; ++s) {
        const int k0 = s * 32;
        short8 ah[4], al[4], bh[2], bl[2];
#pragma unroll
        for (int ct = 0; ct < 4; ++ct) {
            size_t off = (size_t)(by * 64 + ct * 16 + lq) * 256 + k0 + lg * 8;
            ah[ct] = *(const short8*)&wh[off];
            al[ct] = *(const short8*)&wl[off];
        }
#pragma unroll
        for (int nt = 0; nt < 2; ++nt) {
            size_t off = ((size_t)b * N_ + nw + nt * 16 + lq) * 256 + k0 + lg * 8;
            bh[nt] = *(const short8*)&xh[off];
            bl[nt] = *(const short8*)&xl[off];
        }
#pragma unroll
        for (int ct = 0; ct < 4; ++ct)
#pragma unroll
            for (int nt = 0; nt < 2; ++nt) {
                acc[ct][nt] = __builtin_amdgcn_mfma_f32_16x16x32_bf16(ah[ct], bh[nt], acc[ct][nt], 0, 0, 0);
                acc[ct][nt] = __builtin_amdgcn_mfma_f32_16x16x32_bf16(al[ct], bh[nt], acc[ct][nt], 0, 0, 0);
                acc[ct][nt] = __builtin_amdgcn_mfma_f32_16x16x32_bf16(ah[ct], bl[nt], acc[ct][nt], 0, 0, 0);
            }
    }
#pragma unroll
    for (int ct = 0; ct < 4; ++ct) {
        float sv[4], qv[4];
#pragma unroll
        for (int r = 0; r < 4; ++r) {
            float a0 = acc[ct][0][r], a1 = acc[ct][1][r];
            sv[r] = a0 + a1;
            qv[r] = a0 * a0 + a1 * a1;
#pragma unroll
            for (int m = 1; m < 16; m <<= 1) {
                sv[r] += __shfl_xor(sv[r], m);
                qv[r] += __shfl_xor(qv[r], m);
            }
        }
        if (lq == 0) {
#pragma unroll
            for (int r = 0; r < 4; ++r) {
                redS[w][ct * 16 + lg * 4 + r] = sv[r];
                redQ[w][ct * 16 + lg * 4 + r] = qv[r];
            }
        }
    }
    __syncthreads();
    if (t < 64) {
        float s = redS[0][t] + redS[1][t] + redS[2][t] + redS[3][t];
        float q = redQ[0][t] + redQ[1][t] + redQ[2][t] + redQ[3][t];
        atomicAdd(&sums[by * 64 + t], s);
        atomicAdd(&sumsq[by * 64 + t], q);
    }
    if (by == 0) {
        // q/k frag layout: tile = b*256 + n>>4; lane = (n&15)|(((c>>3)&3)<<4); j = c&7
        // c0 = ct*16+lg*4: (c>>3)&3 constant over r=0..3; c&7 = (lg&1)*4 + r  -> b64 store
#pragma unroll
        for (int ct = 0; ct < 4; ++ct)
#pragma unroll
            for (int nt = 0; nt < 2; ++nt) {
                int n = nw + nt * 16 + lq;
                int c0 = ct * 16 + lg * 4;
                bfraw4 v;
#pragma unroll
                for (int r = 0; r < 4; ++r) v[r] = f2bf(acc[ct][nt][r]);
                size_t addr = ((size_t)(b << 8) + (n >> 4)) * 512
                            + (size_t)(((n & 15) | (((c0 >> 3) & 3) << 4)) << 3) + (c0 & 7);
                if (c0 < 32) *(bfraw4*)&qf[addr] = v;
                else         *(bfraw4*)&kfp[addr] = v;
            }
    } else {
        // d path: stage [cl][nl] in LDS (cl = local cg 0..63, nl = local n 0..31),
        // then read in A-frag order and store 1KB coalesced per tile.
#pragma unroll
        for (int ct = 0; ct < 4; ++ct)
#pragma unroll
            for (int nt = 0; nt < 2; ++nt)
#pragma unroll
                for (int r = 0; r < 4; ++r) {
                    int cl = ct * 16 + lg * 4 + r;
                    int nl = nt * 16 + lq;
                    Td[w][cl * 40 + nl] = f2bf(acc[ct][nt][r]);
                }
        __syncthreads();
#pragma unroll
        for (int ctl = 0; ctl < 4; ++ctl) {
            short8 vv = *(const short8*)&Td[w][(ctl * 16 + (l & 15)) * 40 + (l >> 4) * 8];
            size_t addr = (((size_t)(b << 4) + (by - 1) * 4 + ctl) * 128 + (nw >> 5)) * 512
                        + (size_t)l * 8;
            *(short8*)&dfp[addr] = vv;
        }
    }
}

// ---------------------------------------------------------------------------
// in-place bf16 relu(sc*y + bi) over frag-layout planes; BN finalize inline.
// ---------------------------------------------------------------------------
__device__ inline void bn_coef(const float* __restrict__ sums,
                               const float* __restrict__ g1, const float* __restrict__ b1,
                               const float* __restrict__ g2, const float* __restrict__ b2,
                               const float* __restrict__ g3, const float* __restrict__ b3,
                               int ch, float& sc, float& bi)
{
    const float inv = 1.0f / (float)(B_ * N_);
    float mean = sums[ch] * inv;
    float var  = sums[320 + ch] * inv - mean * mean;
    float g, bb;
    if (ch < 32)      { g = g1[ch];      bb = b1[ch]; }
    else if (ch < 64) { g = g2[ch - 32]; bb = b2[ch - 32]; }
    else              { g = g3[ch - 64]; bb = b3[ch - 64]; }
    sc = g * rsqrtf(var + 1e-5f);
    bi = bb - sc * mean;
    if (ch < 32) { sc *= LOG2E; bi *= LOG2E; }
}

__global__ __launch_bounds__(256) void affine_kernel(
    uint8_t* __restrict__ wsb,
    const float* __restrict__ g1, const float* __restrict__ b1,
    const float* __restrict__ g2, const float* __restrict__ b2,
    const float* __restrict__ g3, const float* __restrict__ b3)
{
    bfraw* base = (bfraw*)wsb;
    const float* sums = (const float*)(wsb + SUM_OFF_B);
    size_t i8 = ((size_t)blockIdx.x * 256 + threadIdx.x) * 8;
    bfraw4 v0 = *(bfraw4*)&base[i8];
    bfraw4 v1 = *(bfraw4*)&base[i8 + 4];
    if (i8 < 1048576) {                          // qf or kf
        int ch0 = (((int)(i8 >> 7)) & 3) * 8 + ((i8 < 524288) ? 0 : 32);
        float sa[8], ca[8];
#pragma unroll
        for (int j = 0; j < 8; ++j)
            bn_coef(sums, g1, b1, g2, b2, g3, b3, ch0 + j, sa[j], ca[j]);
#pragma unroll
        for (int j = 0; j < 4; ++j) {
            v0[j] = f2bf(fmaxf(0.f, fmaf(sa[j],     bf2f(v0[j]), ca[j])));
            v1[j] = f2bf(fmaxf(0.f, fmaf(sa[j + 4], bf2f(v1[j]), ca[j + 4])));
        }
    } else {                                     // df
        size_t rel = i8 - 1048576;
        int ch = 64 + (((int)(rel >> 16)) & 15) * 16 + (((int)(rel >> 3)) & 15);
        float s, b;
        bn_coef(sums, g1, b1, g2, b2, g3, b3, ch, s, b);
#pragma unroll
        for (int j = 0; j < 4; ++j) {
            v0[j] = f2bf(fmaxf(0.f, fmaf(s, bf2f(v0[j]), b)));
            v1[j] = f2bf(fmaxf(0.f, fmaf(s, bf2f(v1[j]), b)));
        }
    }
    *(bfraw4*)&base[i8] = v0;
    *(bfraw4*)&base[i8 + 4] = v1;
}

// ---------------------------------------------------------------------------
// flash v12 = R9 structure with TK=512 -> 8 fat phases (was 16).
// Measured trend: 32ph=61us, 16ph=52.5/47.4us -- per-phase fixed cost
// (barrier drain + score->write serial head) dominates, so halve the phase
// count again.  Score runs in TWO register-reusing sub-rounds of 8 MFMA
// (st[8]/kfr[8] live sets unchanged vs R9 -> VGPR stays ~120).  PV: 16
// chunks with the same rolling dfr[2][8] window.  Homogeneous waves (R11
// lesson: producer/consumer specialization loses at 2 waves/SIMD).
// Fixed-shift softmax P = exp2(s-16) (validated R7-R11).
// LDS: Pl 2x64KB + lsh = 128.5KB, grid 256 = 1 block/CU (unchanged).
// ---------------------------------------------------------------------------
__global__ __launch_bounds__(512, 2) void flash_kernel(
    const float* __restrict__ x, const uint8_t* __restrict__ wsb,
    float* __restrict__ out)
{
    const bfraw* qf  = (const bfraw*)wsb;
    const bfraw* kfp = (const bfraw*)(wsb + KF_OFF_B);
    const bfraw* dfp = (const bfraw*)(wsb + DF_OFF_B);
    __shared__ bfraw Pl[2][64 * 512];            // 128 KB
    __shared__ float lsh[2][64];                 // sum[k-half][q]

    const int id  = blockIdx.x;
    const int b   = id & 3;
    const int n0q = (id >> 2) << 6;
    const int tid = threadIdx.x;
    const int w   = tid >> 6;                    // 0..7
    const int l   = tid & 63;
    const int lq  = l & 15;
    const int lg  = l >> 4;
    const int sw  = lq & 7;
    const int qt_s   = w >> 1;                   // score q-tile 0..3
    const int ks_loc = w & 1;                    // score k-half (16 tiles)
    const int ctg0 = w;                          // PV c-tiles (d-dup = 1)
    const int ctg1 = 8 + w;

    const short8 qfrag = *(const short8*)&qf[((size_t)(b * 256 + (n0q >> 4) + qt_s)) * 512 + l * 8];
    const float4v zv = {-16.f, -16.f, -16.f, -16.f};   // fixed log2 shift

    float ps = 0.f;
    float4v acc[2][4];                           // [ct][qt]
#pragma unroll
    for (int i = 0; i < 2; ++i)
#pragma unroll
        for (int j = 0; j < 4; ++j) acc[i][j] = (float4v){0.f, 0.f, 0.f, 0.f};

    short8 dfr[2][8];                            // rolling 8-chunk window
#pragma unroll
    for (int ch = 0; ch < 8; ++ch) {
        dfr[0][ch] = *(const short8*)&dfp[(((size_t)(b * 16 + ctg0)) * 128 + ch) * 512 + l * 8];
        dfr[1][ch] = *(const short8*)&dfp[(((size_t)(b * 16 + ctg1)) * 128 + ch) * 512 + l * 8];
    }
    short8 kfr[8];                               // register-resident k fragments
#pragma unroll
    for (int kt = 0; kt < 8; ++kt)               // phase 0, sub-round A
        kfr[kt] = *(const short8*)&kfp[((size_t)(b * 256 + ks_loc * 16 + kt)) * 512 + l * 8];

    const int qrow = qt_s * 16 + lq;
    for (int it = 0; it < 8; ++it) {
        const int ib = it & 1;
        const int nit = (it + 1) & 7;
        // ==== score sub-round A: k-tiles it*32 + ks_loc*16 + 0..7 ====
        float4v st[8];
#pragma unroll
        for (int kt = 0; kt < 8; ++kt)
            st[kt] = __builtin_amdgcn_mfma_f32_16x16x32_bf16(kfr[kt], qfrag, zv, 0, 0, 0);
#pragma unroll
        for (int kt = 0; kt < 8; ++kt)           // prefetch sub-round B
            kfr[kt] = *(const short8*)&kfp[((size_t)(b * 256 + it * 32 + ks_loc * 16 + 8 + kt)) * 512 + l * 8];
#pragma unroll
        for (int kt = 0; kt < 8; ++kt) {
            float e0 = EXP2(st[kt][0]);
            float e1 = EXP2(st[kt][1]);
            float e2 = EXP2(st[kt][2]);
            float e3 = EXP2(st[kt][3]);
            ps += (e0 + e1) + (e2 + e3);
            uint2 pd = {pack2(e0, e1), pack2(e2, e3)};
            int g = (2 * (ks_loc * 16 + kt) + (lg >> 1)) ^ sw;
            *(uint2*)&Pl[ib][qrow * 512 + g * 8 + (lg & 1) * 4] = pd;
        }
        // ==== score sub-round B: k-tiles it*32 + ks_loc*16 + 8..15 ====
#pragma unroll
        for (int kt = 0; kt < 8; ++kt)
            st[kt] = __builtin_amdgcn_mfma_f32_16x16x32_bf16(kfr[kt], qfrag, zv, 0, 0, 0);
#pragma unroll
        for (int kt = 0; kt < 8; ++kt)           // prefetch next phase sub-round A
            kfr[kt] = *(const short8*)&kfp[((size_t)(b * 256 + nit * 32 + ks_loc * 16 + kt)) * 512 + l * 8];
#pragma unroll
        for (int kt = 0; kt < 8; ++kt) {
            float e0 = EXP2(st[kt][0]);
            float e1 = EXP2(st[kt][1]);
            float e2 = EXP2(st[kt][2]);
            float e3 = EXP2(st[kt][3]);
            ps += (e0 + e1) + (e2 + e3);
            uint2 pd = {pack2(e0, e1), pack2(e2, e3)};
            int g = (2 * (ks_loc * 16 + 8 + kt) + (lg >> 1)) ^ sw;
            *(uint2*)&Pl[ib][qrow * 512 + g * 8 + (lg & 1) * 4] = pd;
        }
        __syncthreads();
        // ==== PV: 2 ctiles x 4 q-tiles x 16 chunks ====
#pragma unroll
        for (int ch = 0; ch < 16; ++ch) {
            short8 bfr[4];
            int g = (ch * 4 + lg) ^ sw;
#pragma unroll
            for (int qt = 0; qt < 4; ++qt)
                bfr[qt] = *(const short8*)&Pl[ib][(qt * 16 + lq) * 512 + g * 8];
            __builtin_amdgcn_s_setprio(1);
#pragma unroll
            for (int qt = 0; qt < 4; ++qt) {
                acc[0][qt] = __builtin_amdgcn_mfma_f32_16x16x32_bf16(dfr[0][ch & 7], bfr[qt], acc[0][qt], 0, 0, 0);
                acc[1][qt] = __builtin_amdgcn_mfma_f32_16x16x32_bf16(dfr[1][ch & 7], bfr[qt], acc[1][qt], 0, 0, 0);
            }
            __builtin_amdgcn_s_setprio(0);
            // rolling reload: ch<8 -> this phase's chunks ch+8; else next phase's ch-8
            int rch = (ch < 8) ? (it * 16 + ch + 8) : (nit * 16 + ch - 8);
            dfr[0][ch & 7] = *(const short8*)&dfp[(((size_t)(b * 16 + ctg0)) * 128 + rch) * 512 + l * 8];
            dfr[1][ch & 7] = *(const short8*)&dfp[(((size_t)(b * 16 + ctg1)) * 128 + rch) * 512 + l * 8];
        }
    }
    // ---- publish per-(half,q) sums ----
    ps += __shfl_xor(ps, 16);
    ps += __shfl_xor(ps, 32);
    if (lg == 0) lsh[ks_loc][qrow] = ps;
    __syncthreads();
    // ---- epilogue: normalize, out = x + O ----
    float inv[4];
#pragma unroll
    for (int qt = 0; qt < 4; ++qt) {
        int qg = qt * 16 + lq;
        inv[qt] = 1.0f / (lsh[0][qg] + lsh[1][qg]);
    }
#pragma unroll
    for (int ct = 0; ct < 2; ++ct) {
        int ctg = ct ? ctg1 : ctg0;
#pragma unroll
        for (int r = 0; r < 4; ++r) {
            int c = ctg * 16 + lg * 4 + r;
            size_t base = ((size_t)b * C_ + c) * N_ + n0q;
#pragma unroll
            for (int qt = 0; qt < 4; ++qt) {
                size_t idx = base + qt * 16 + lq;
                out[idx] = x[idx] + acc[ct][qt][r] * inv[qt];
            }
        }
    }
}

extern "C" void kernel_launch(void* const* d_in, const int* in_sizes, int n_in,
                              void* d_out, int out_size, void* d_ws, size_t ws_size,
                              hipStream_t stream) {
    (void)in_sizes; (void)n_in; (void)out_size; (void)ws_size;
    const float* x  = (const float*)d_in[0];
    const float* w1 = (const float*)d_in[1];
    const float* w2 = (const float*)d_in[2];
    const float* w3 = (const float*)d_in[3];
    const float* g1 = (const float*)d_in[4];
    const float* b1 = (const float*)d_in[5];
    const float* g2 = (const float*)d_in[6];
    const float* b2 = (const float*)d_in[7];
    const float* g3 = (const float*)d_in[8];
    const float* b3 = (const float*)d_in[9];
    uint8_t* wsb = (uint8_t*)d_ws;
    float* outp = (float*)d_out;

    prep_kernel<<<1104, 256, 0, stream>>>(x, w1, w2, w3, wsb);
    ygemm_kernel<<<dim3(128, 5), 256, 0, stream>>>(wsb);
    affine_kernel<<<2560, 256, 0, stream>>>(wsb, g1, b1, g2, b2, g3, b3);
    flash_kernel<<<256, 512, 0, stream>>>(x, wsb, outp);
}